// Round 3
// baseline (240.109 us; speedup 1.0000x reference)
//
#include <hip/hip_runtime.h>
#include <math.h>

// Problem constants (fixed by setup_inputs)
constexpr int HOPS  = 3;
constexpr int VOCAB = 50257;
constexpr int DIM   = 128;
constexpr int NB    = 32;         // batch
constexpr int NM    = 512;        // story slots
constexpr int NS    = 6;          // tokens per story slot
constexpr int NT    = 128;        // trees
constexpr int NL    = 64;         // tokens per tree
constexpr int SLOTS = NM + NT;    // 640
constexpr size_t TS = (size_t)VOCAB * DIM;              // table stride in C
constexpr size_t TABSTRIDE = (size_t)NB * SLOTS * DIM;  // msum stride per table
constexpr int CHUNKS = SLOTS / 64;                      // 10 slot-chunks of 64
constexpr int TREE_BLOCKS  = NB * NT / 4;               // 1024 (1 wave/tree)
constexpr int STORY_BLOCKS = NB * NM / 4;               // 4096 (1 wave/slot)

// msum holds gather-sums for tables 1..3 only (table 0 is dead: u=0 at hop 0
// makes the first softmax uniform independent of m_A). msum index k = C[k+1].

__device__ __forceinline__ void addf4(float4& a, const float4& v) {
    a.x += v.x; a.y += v.y; a.z += v.z; a.w += v.w;
}
__device__ __forceinline__ void halfred(float4& a) {   // sum lane halves (xor 32)
    a.x += __shfl_xor(a.x, 32); a.y += __shfl_xor(a.y, 32);
    a.z += __shfl_xor(a.z, 32); a.w += __shfl_xor(a.w, 32);
}

// ---------------------------------------------------------------------------
// Fused gather: blocks [0,TREE_BLOCKS) handle trees (1 wave per 64-token
// tree), the rest handle story slots (1 wave per 6-token slot). Lane split:
// half = token parity, 32 lanes x float4 cover the 128-dim row; 3 tables
// accumulated per token (same indices).
// ---------------------------------------------------------------------------
__global__ __launch_bounds__(256) void gather_fused(
    const float* __restrict__ C, const int* __restrict__ story,
    const int* __restrict__ kb, float* __restrict__ msum)
{
    const int wave = threadIdx.x >> 6, lane = threadIdx.x & 63;
    const int half = lane >> 5, q = lane & 31;
    const float* Cb = C + TS + (size_t)q * 4;     // table 1 base, this lane's dims
    float4 a0 = {0,0,0,0}, a1 = {0,0,0,0}, a2 = {0,0,0,0};

    if (blockIdx.x < TREE_BLOCKS) {
        const int g = blockIdx.x * 4 + wave;      // b*NT + tree
        const int tok = kb[(size_t)g * NL + lane]; // one coalesced 64-token load
        #pragma unroll 8
        for (int i = 0; i < NL / 2; ++i) {
            int s = __shfl(tok, 2 * i + half);
            const float* p = Cb + (size_t)s * DIM;
            addf4(a0, *(const float4*)(p));
            addf4(a1, *(const float4*)(p + TS));
            addf4(a2, *(const float4*)(p + 2 * TS));
        }
        halfred(a0); halfred(a1); halfred(a2);
        if (half == 0) {
            const int b = g >> 7, tr = g & (NT - 1);
            const size_t o = ((size_t)b * SLOTS + NM + tr) * DIM + q * 4;
            *(float4*)(msum + o)                 = a0;
            *(float4*)(msum + o + TABSTRIDE)     = a1;
            *(float4*)(msum + o + 2 * TABSTRIDE) = a2;
        }
    } else {
        const int g = (blockIdx.x - TREE_BLOCKS) * 4 + wave;  // b*NM + slot
        const int* idx = story + (size_t)g * NS;
        int tok = (lane < NS) ? idx[lane] : 0;
        #pragma unroll
        for (int i = 0; i < NS / 2; ++i) {
            int s = __shfl(tok, 2 * i + half);
            const float* p = Cb + (size_t)s * DIM;
            addf4(a0, *(const float4*)(p));
            addf4(a1, *(const float4*)(p + TS));
            addf4(a2, *(const float4*)(p + 2 * TS));
        }
        halfred(a0); halfred(a1); halfred(a2);
        if (half == 0) {
            const int b = g >> 9, slot = g & (NM - 1);
            const size_t o = ((size_t)b * SLOTS + slot) * DIM + q * 4;
            *(float4*)(msum + o)                 = a0;
            *(float4*)(msum + o + TABSTRIDE)     = a1;
            *(float4*)(msum + o + 2 * TABSTRIDE) = a2;
        }
    }
}

// ---------------------------------------------------------------------------
// Hop 0: softmax(0) is uniform -> u = (1/SLOTS) * sum_m mC[m]. One block per
// b, writes u directly (no memset, no atomics).
// ---------------------------------------------------------------------------
__global__ __launch_bounds__(256) void hop0_k(
    const float* __restrict__ msum, float* __restrict__ u)
{
    const int b = blockIdx.x, t = threadIdx.x, d = t & (DIM - 1), sub = t >> 7;
    const float* mC = msum + ((size_t)b * SLOTS + sub * (SLOTS / 2)) * DIM + d;
    float acc = 0.f;
    #pragma unroll 16
    for (int m = 0; m < SLOTS / 2; ++m) acc += mC[(size_t)m * DIM];
    __shared__ float red[256];
    red[t] = acc;
    __syncthreads();
    if (t < DIM) u[b * DIM + t] = (red[t] + red[t + 128]) * (1.f / SLOTS);
}

// ---------------------------------------------------------------------------
// Scores + softmax fused: one block per b. u cached in LDS; thread t scores
// slots {t, t+256, t+512(if t<128)}; block-wide max/sum; writes probs.
// ---------------------------------------------------------------------------
__device__ __forceinline__ float dot128(const float* __restrict__ row,
                                        const float* __restrict__ u_s)
{
    float4 acc = {0.f, 0.f, 0.f, 0.f};
    #pragma unroll
    for (int i = 0; i < DIM / 4; ++i) {
        float4 r  = ((const float4*)row)[i];
        float4 uu = ((const float4*)u_s)[i];
        acc.x = fmaf(r.x, uu.x, acc.x);
        acc.y = fmaf(r.y, uu.y, acc.y);
        acc.z = fmaf(r.z, uu.z, acc.z);
        acc.w = fmaf(r.w, uu.w, acc.w);
    }
    return (acc.x + acc.y) + (acc.z + acc.w);
}

__global__ __launch_bounds__(256) void scores_softmax_k(
    const float* __restrict__ msum, const float* __restrict__ u,
    float* __restrict__ sc, int tab)
{
    const int b = blockIdx.x, t = threadIdx.x, wv = t >> 6, ln = t & 63;
    __shared__ float u_s[DIM];
    __shared__ float red[4];
    if (t < DIM) u_s[t] = u[b * DIM + t];
    __syncthreads();

    const float* mA = msum + (size_t)tab * TABSTRIDE + (size_t)b * SLOTS * DIM;
    float s0 = dot128(mA + (size_t)t * DIM, u_s);
    float s1 = dot128(mA + (size_t)(t + 256) * DIM, u_s);
    float s2 = (t < SLOTS - 512) ? dot128(mA + (size_t)(t + 512) * DIM, u_s)
                                 : -INFINITY;

    float lmax = fmaxf(fmaxf(s0, s1), s2);
    #pragma unroll
    for (int off = 32; off > 0; off >>= 1) lmax = fmaxf(lmax, __shfl_xor(lmax, off));
    if (ln == 0) red[wv] = lmax;
    __syncthreads();
    lmax = fmaxf(fmaxf(red[0], red[1]), fmaxf(red[2], red[3]));
    __syncthreads();

    float e0 = expf(s0 - lmax), e1 = expf(s1 - lmax);
    float e2 = (t < SLOTS - 512) ? expf(s2 - lmax) : 0.f;
    float lsum = e0 + e1 + e2;
    #pragma unroll
    for (int off = 32; off > 0; off >>= 1) lsum += __shfl_xor(lsum, off);
    if (ln == 0) red[wv] = lsum;
    __syncthreads();
    const float inv = 1.0f / (red[0] + red[1] + red[2] + red[3]);

    float* s = sc + b * SLOTS;
    s[t] = e0 * inv;
    s[t + 256] = e1 * inv;
    if (t < SLOTS - 512) s[t + 512] = e2 * inv;
}

// ---------------------------------------------------------------------------
// Weighted sum: u[b] += sum_m probs[b][m] * mC[b][m]. Partial per 64-slot
// chunk, atomicAdd into u (u already holds the running value).
// ---------------------------------------------------------------------------
__global__ __launch_bounds__(256) void weighted_k(
    const float* __restrict__ msum, const float* __restrict__ probs,
    float* __restrict__ u, int tab)
{
    const int b = blockIdx.x / CHUNKS, chunk = blockIdx.x % CHUNKS;
    const int t = threadIdx.x, d = t & (DIM - 1), sub = t >> 7;
    __shared__ float p[64];
    if (t < 64) p[t] = probs[b * SLOTS + chunk * 64 + t];
    __syncthreads();
    const float* mC = msum + (size_t)tab * TABSTRIDE +
                      ((size_t)b * SLOTS + chunk * 64 + sub * 32) * DIM + d;
    float acc = 0.f;
    #pragma unroll
    for (int m = 0; m < 32; ++m) acc = fmaf(p[sub * 32 + m], mC[(size_t)m * DIM], acc);
    __shared__ float red[256];
    red[t] = acc;
    __syncthreads();
    if (t < DIM) atomicAdd(&u[b * DIM + d], red[t] + red[t + 128]);
}

extern "C" void kernel_launch(void* const* d_in, const int* in_sizes, int n_in,
                              void* d_out, int out_size, void* d_ws, size_t ws_size,
                              hipStream_t stream) {
    const float* C     = (const float*)d_in[0];   // [4][VOCAB][DIM] fp32
    const int*   story = (const int*)d_in[1];     // [32][512][6]
    const int*   kb    = (const int*)d_in[2];     // [32][128][64]
    float*       u     = (float*)d_out;           // [32][128] fp32 — also the accumulator
    float*       msum  = (float*)d_ws;            // [3][32][640][128] fp32 = 31.5 MiB
    float*       sc    = msum + 3 * TABSTRIDE;    // [32][640] scores/probs

    gather_fused<<<TREE_BLOCKS + STORY_BLOCKS, 256, 0, stream>>>(C, story, kb, msum);
    hop0_k<<<NB, 256, 0, stream>>>(msum /*tab0 = C[1]*/, u);

    for (int hop = 1; hop < HOPS; ++hop) {
        // A-table of hop h is C[h] -> msum index h-1; V-table C[h+1] -> index h
        scores_softmax_k<<<NB, 256, 0, stream>>>(msum, u, sc, hop - 1);
        weighted_k<<<NB * CHUNKS, 256, 0, stream>>>(msum, sc, u, hop);
    }
}

// Round 4
// 221.120 us; speedup vs baseline: 1.0859x; 1.0859x over previous
//
#include <hip/hip_runtime.h>
#include <math.h>

// Problem constants (fixed by setup_inputs)
constexpr int HOPS  = 3;
constexpr int VOCAB = 50257;
constexpr int DIM   = 128;
constexpr int NB    = 32;         // batch
constexpr int NM    = 512;        // story slots
constexpr int NS    = 6;          // tokens per story slot
constexpr int NT    = 128;        // trees
constexpr int NL    = 64;         // tokens per tree
constexpr int SLOTS = NM + NT;    // 640
constexpr size_t TS = (size_t)VOCAB * DIM;              // fp32 table stride in C
constexpr size_t TABSTRIDE = (size_t)NB * SLOTS * DIM;  // msum per-table stride (fp16 elems)
constexpr int CHUNKS = SLOTS / 64;                      // 10

// fp16 compressed tables, token-interleaved: Ch[v][tab][d], tab in 0..2 = C[1..3].
// One token's 3 rows = 768 B contiguous (12 cache lines, sequential).
constexpr size_t CH_ELEMS = (size_t)VOCAB * 3 * DIM;    // 19,298,688
constexpr int NE8 = (int)(CH_ELEMS / 8);                // 2,412,336 half8 groups

typedef _Float16 half8 __attribute__((ext_vector_type(8)));

// Gather grid: 1 wave = 4 slots (one per 16-lane quarter). 4 waves/block.
constexpr int TREE_BLOCKS  = NB * NT / 16;   // 256
constexpr int STORY_BLOCKS = NB * NM / 16;   // 1024
constexpr int GATHER_BLOCKS = TREE_BLOCKS + STORY_BLOCKS;  // 1280 (1:4 interleave)

// ---------------------------------------------------------------------------
// Convert C[1..3] fp32 -> Ch fp16 interleaved [V][3][128]. Output-linear;
// each thread converts 8 elements (2 float4 reads, 1 half8 write).
// ---------------------------------------------------------------------------
__global__ __launch_bounds__(256) void convert_k(
    const float* __restrict__ C, _Float16* __restrict__ Ch)
{
    const int e8 = blockIdx.x * 256 + threadIdx.x;
    if (e8 >= NE8) return;
    const size_t base = (size_t)e8 * 8;
    const size_t v    = base / 384;
    const int    rem  = (int)(base % 384);
    const int    tab  = rem >> 7;            // 0..2
    const int    d    = rem & 127;           // 8-aligned
    const float* src = C + (size_t)(1 + tab) * TS + v * DIM + d;
    float4 f0 = *(const float4*)(src);
    float4 f1 = *(const float4*)(src + 4);
    half8 h;
    h[0] = (_Float16)f0.x; h[1] = (_Float16)f0.y;
    h[2] = (_Float16)f0.z; h[3] = (_Float16)f0.w;
    h[4] = (_Float16)f1.x; h[5] = (_Float16)f1.y;
    h[6] = (_Float16)f1.z; h[7] = (_Float16)f1.w;
    *(half8*)(Ch + base) = h;
}

// ---------------------------------------------------------------------------
// Fused gather from fp16 tables. Each 16-lane quarter owns one slot; lane
// l16 owns dims [l16*8, l16*8+8) (one half8 = 256 B row per quarter). No
// cross-lane reduction. fp32 accumulate, fp16 msum store.
// Blocks interleaved 1 tree : 4 story for CU load balance.
// ---------------------------------------------------------------------------
__global__ __launch_bounds__(256) void gather_fused(
    const _Float16* __restrict__ Ch, const int* __restrict__ story,
    const int* __restrict__ kb, _Float16* __restrict__ msum)
{
    const int wave = threadIdx.x >> 6, lane = threadIdx.x & 63;
    const int q = lane >> 4, l16 = lane & 15;
    const int qbase = lane & 48;            // first lane of my quarter

    float a0[8] = {0,0,0,0,0,0,0,0};
    float a1[8] = {0,0,0,0,0,0,0,0};
    float a2[8] = {0,0,0,0,0,0,0,0};

    const bool is_tree = (blockIdx.x % 5) == 0;
    int b, slot;

    if (is_tree) {
        const int g = (blockIdx.x / 5) * 16 + wave * 4 + q;   // b*NT + tree
        b = g >> 7; slot = NM + (g & (NT - 1));
        const int* idx = kb + (size_t)g * NL;
        #pragma unroll
        for (int o = 0; o < 4; ++o) {
            const int tokv = idx[o * 16 + l16];               // coalesced per quarter
            #pragma unroll
            for (int i = 0; i < 16; ++i) {
                const int s = __shfl(tokv, qbase + i);
                const _Float16* p = Ch + (size_t)s * (3 * DIM) + l16 * 8;
                half8 v0 = *(const half8*)(p);
                half8 v1 = *(const half8*)(p + DIM);
                half8 v2 = *(const half8*)(p + 2 * DIM);
                #pragma unroll
                for (int j = 0; j < 8; ++j) {
                    a0[j] += (float)v0[j];
                    a1[j] += (float)v1[j];
                    a2[j] += (float)v2[j];
                }
            }
        }
    } else {
        const int sb = blockIdx.x - blockIdx.x / 5 - 1;       // story block index
        const int g = sb * 16 + wave * 4 + q;                 // b*NM + slot
        b = g >> 9; slot = g & (NM - 1);
        const int* idx = story + (size_t)g * NS;
        const int tokv = (l16 < NS) ? idx[l16] : 0;
        #pragma unroll
        for (int i = 0; i < NS; ++i) {
            const int s = __shfl(tokv, qbase + i);
            const _Float16* p = Ch + (size_t)s * (3 * DIM) + l16 * 8;
            half8 v0 = *(const half8*)(p);
            half8 v1 = *(const half8*)(p + DIM);
            half8 v2 = *(const half8*)(p + 2 * DIM);
            #pragma unroll
            for (int j = 0; j < 8; ++j) {
                a0[j] += (float)v0[j];
                a1[j] += (float)v1[j];
                a2[j] += (float)v2[j];
            }
        }
    }

    const size_t o = ((size_t)b * SLOTS + slot) * DIM + l16 * 8;
    half8 h0, h1, h2;
    #pragma unroll
    for (int j = 0; j < 8; ++j) {
        h0[j] = (_Float16)a0[j]; h1[j] = (_Float16)a1[j]; h2[j] = (_Float16)a2[j];
    }
    *(half8*)(msum + o)                 = h0;
    *(half8*)(msum + o + TABSTRIDE)     = h1;
    *(half8*)(msum + o + 2 * TABSTRIDE) = h2;
}

// ---------------------------------------------------------------------------
// Hop 0: softmax(0) uniform -> u = (1/SLOTS) * sum_m mC[m]. One block per b.
// ---------------------------------------------------------------------------
__global__ __launch_bounds__(256) void hop0_k(
    const _Float16* __restrict__ msum, float* __restrict__ u)
{
    const int b = blockIdx.x, t = threadIdx.x, d = t & (DIM - 1), sub = t >> 7;
    const _Float16* mC = msum + ((size_t)b * SLOTS + sub * (SLOTS / 2)) * DIM + d;
    float acc = 0.f;
    #pragma unroll 16
    for (int m = 0; m < SLOTS / 2; ++m) acc += (float)mC[(size_t)m * DIM];
    __shared__ float red[256];
    red[t] = acc;
    __syncthreads();
    if (t < DIM) u[b * DIM + t] = (red[t] + red[t + 128]) * (1.f / SLOTS);
}

// ---------------------------------------------------------------------------
// Scores + softmax fused: one block per b; u in LDS; writes probs (fp32).
// ---------------------------------------------------------------------------
__device__ __forceinline__ float dot128h(const _Float16* __restrict__ row,
                                         const float* __restrict__ u_s)
{
    float acc = 0.f;
    const half8* r8 = (const half8*)row;
    #pragma unroll
    for (int i = 0; i < DIM / 8; ++i) {
        half8 h = r8[i];
        #pragma unroll
        for (int j = 0; j < 8; ++j) acc = fmaf((float)h[j], u_s[8 * i + j], acc);
    }
    return acc;
}

__global__ __launch_bounds__(256) void scores_softmax_k(
    const _Float16* __restrict__ msum, const float* __restrict__ u,
    float* __restrict__ sc, int tab)
{
    const int b = blockIdx.x, t = threadIdx.x, wv = t >> 6, ln = t & 63;
    __shared__ float u_s[DIM];
    __shared__ float red[4];
    if (t < DIM) u_s[t] = u[b * DIM + t];
    __syncthreads();

    const _Float16* mA = msum + (size_t)tab * TABSTRIDE + (size_t)b * SLOTS * DIM;
    float s0 = dot128h(mA + (size_t)t * DIM, u_s);
    float s1 = dot128h(mA + (size_t)(t + 256) * DIM, u_s);
    float s2 = (t < SLOTS - 512) ? dot128h(mA + (size_t)(t + 512) * DIM, u_s)
                                 : -INFINITY;

    float lmax = fmaxf(fmaxf(s0, s1), s2);
    #pragma unroll
    for (int off = 32; off > 0; off >>= 1) lmax = fmaxf(lmax, __shfl_xor(lmax, off));
    if (ln == 0) red[wv] = lmax;
    __syncthreads();
    lmax = fmaxf(fmaxf(red[0], red[1]), fmaxf(red[2], red[3]));
    __syncthreads();

    float e0 = expf(s0 - lmax), e1 = expf(s1 - lmax);
    float e2 = (t < SLOTS - 512) ? expf(s2 - lmax) : 0.f;
    float lsum = e0 + e1 + e2;
    #pragma unroll
    for (int off = 32; off > 0; off >>= 1) lsum += __shfl_xor(lsum, off);
    if (ln == 0) red[wv] = lsum;
    __syncthreads();
    const float inv = 1.0f / (red[0] + red[1] + red[2] + red[3]);

    float* s = sc + b * SLOTS;
    s[t] = e0 * inv;
    s[t + 256] = e1 * inv;
    if (t < SLOTS - 512) s[t + 512] = e2 * inv;
}

// ---------------------------------------------------------------------------
// Weighted sum: u[b] += sum_m probs[b][m] * mC[b][m]; 64-slot chunks, atomic.
// ---------------------------------------------------------------------------
__global__ __launch_bounds__(256) void weighted_k(
    const _Float16* __restrict__ msum, const float* __restrict__ probs,
    float* __restrict__ u, int tab)
{
    const int b = blockIdx.x / CHUNKS, chunk = blockIdx.x % CHUNKS;
    const int t = threadIdx.x, d = t & (DIM - 1), sub = t >> 7;
    __shared__ float p[64];
    if (t < 64) p[t] = probs[b * SLOTS + chunk * 64 + t];
    __syncthreads();
    const _Float16* mC = msum + (size_t)tab * TABSTRIDE +
                         ((size_t)b * SLOTS + chunk * 64 + sub * 32) * DIM + d;
    float acc = 0.f;
    #pragma unroll
    for (int m = 0; m < 32; ++m)
        acc = fmaf(p[sub * 32 + m], (float)mC[(size_t)m * DIM], acc);
    __shared__ float red[256];
    red[t] = acc;
    __syncthreads();
    if (t < DIM) atomicAdd(&u[b * DIM + d], red[t] + red[t + 128]);
}

extern "C" void kernel_launch(void* const* d_in, const int* in_sizes, int n_in,
                              void* d_out, int out_size, void* d_ws, size_t ws_size,
                              hipStream_t stream) {
    const float* C     = (const float*)d_in[0];   // [4][VOCAB][DIM] fp32
    const int*   story = (const int*)d_in[1];     // [32][512][6]
    const int*   kb    = (const int*)d_in[2];     // [32][128][64]
    float*       u     = (float*)d_out;           // [32][128] fp32 accumulator

    _Float16* Ch   = (_Float16*)d_ws;             // [V][3][128] fp16 = 36.8 MiB
    _Float16* msum = Ch + CH_ELEMS;               // [3][NB][SLOTS][128] fp16 = 15 MiB
    float*    sc   = (float*)(msum + 3 * TABSTRIDE);  // [NB][SLOTS] probs

    convert_k<<<(NE8 + 255) / 256, 256, 0, stream>>>(C, Ch);
    gather_fused<<<GATHER_BLOCKS, 256, 0, stream>>>(Ch, story, kb, msum);
    hop0_k<<<NB, 256, 0, stream>>>(msum /*tab0 = C[1]*/, u);

    for (int hop = 1; hop < HOPS; ++hop) {
        // A-table of hop h is C[h] -> msum index h-1; V-table C[h+1] -> index h
        scores_softmax_k<<<NB, 256, 0, stream>>>(msum, u, sc, hop - 1);
        weighted_k<<<NB * CHUNKS, 256, 0, stream>>>(msum, sc, u, hop);
    }
}